// Round 2
// baseline (1180.293 us; speedup 1.0000x reference)
//
#include <hip/hip_runtime.h>
#include <stdint.h>
#include <stddef.h>

#define T_TOK 1024
#define NE    16
#define TOPK  4
#define HID   2048
#define INTER 2048
#define CAP   512          // 2*T*K/E
#define GLIMIT 7.0f
#define GALPHA 1.702f

#define BM  128
#define BK  64             // i8 MFMA: K=64 per step

typedef __attribute__((ext_vector_type(4))) int   iv4;

// global_load_lds helper: 16B per lane, LDS dest = wave-uniform base + lane*16
typedef const __attribute__((address_space(1))) unsigned gl_u32;
typedef __attribute__((address_space(3))) unsigned lds_u32;
__device__ __forceinline__ void gl_lds16(const void* g, void* l) {
    __builtin_amdgcn_global_load_lds((gl_u32*)g, (lds_u32*)l, 16, 0, 0);
}

__device__ __forceinline__ int pack4(float a, float b, float c, float d) {
    int qa = (int)a, qb = (int)b, qc = (int)c, qd = (int)d;   // weights are integral f32
    return (qa & 255) | ((qb & 255) << 8) | ((qc & 255) << 16) | (qd << 24);
}

// ---------------- gating: softmax + top4 + renormalize ----------------
__global__ __launch_bounds__(256) void gating_kernel(
    const float* __restrict__ logits, int* __restrict__ topki, float* __restrict__ topkw)
{
    int t = blockIdx.x * 256 + threadIdx.x;
    if (t >= T_TOK) return;
    float l[NE];
#pragma unroll
    for (int e = 0; e < NE; e++) l[e] = logits[t * NE + e];
    unsigned used = 0;
    float val[TOPK]; int idx[TOPK];
#pragma unroll
    for (int k = 0; k < TOPK; k++) {
        float bv = -3.4e38f; int bi = 0;
#pragma unroll
        for (int e = 0; e < NE; e++) {
            bool ok = (((used >> e) & 1u) == 0u) && (l[e] > bv);
            bv = ok ? l[e] : bv;
            bi = ok ? e : bi;
        }
        used |= (1u << bi); idx[k] = bi; val[k] = bv;
    }
    float m = val[0];
    float s = 0.f, w[TOPK];
#pragma unroll
    for (int k = 0; k < TOPK; k++) { w[k] = expf(val[k] - m); s += w[k]; }
    float inv = 1.0f / s;
#pragma unroll
    for (int k = 0; k < TOPK; k++) { topki[t * TOPK + k] = idx[k]; topkw[t * TOPK + k] = w[k] * inv; }
}

// ---------------- per-token dynamic int8 quant ----------------
__global__ __launch_bounds__(256) void quant_x_kernel(
    const float* __restrict__ x, char* __restrict__ xq, float* __restrict__ xs)
{
    int t = blockIdx.x;
    const float4* row = (const float4*)(x + (size_t)t * HID);
    __shared__ float red[256];
    float4 v0 = row[threadIdx.x];
    float4 v1 = row[threadIdx.x + 256];
    float amax = fmaxf(fmaxf(fabsf(v0.x), fabsf(v0.y)), fmaxf(fabsf(v0.z), fabsf(v0.w)));
    amax = fmaxf(amax, fmaxf(fmaxf(fabsf(v1.x), fabsf(v1.y)), fmaxf(fabsf(v1.z), fabsf(v1.w))));
    red[threadIdx.x] = amax; __syncthreads();
    for (int s = 128; s > 0; s >>= 1) {
        if (threadIdx.x < s) red[threadIdx.x] = fmaxf(red[threadIdx.x], red[threadIdx.x + s]);
        __syncthreads();
    }
    float scale = fmaxf(red[0] / 127.0f, 1e-8f);
    if (threadIdx.x == 0) xs[t] = scale;
    char4* orow = (char4*)(xq + (size_t)t * HID);
    {
        char4 c;
        c.x = (char)fminf(fmaxf(rintf(v0.x / scale), -127.f), 127.f);
        c.y = (char)fminf(fmaxf(rintf(v0.y / scale), -127.f), 127.f);
        c.z = (char)fminf(fmaxf(rintf(v0.z / scale), -127.f), 127.f);
        c.w = (char)fminf(fmaxf(rintf(v0.w / scale), -127.f), 127.f);
        orow[threadIdx.x] = c;
        c.x = (char)fminf(fmaxf(rintf(v1.x / scale), -127.f), 127.f);
        c.y = (char)fminf(fmaxf(rintf(v1.y / scale), -127.f), 127.f);
        c.z = (char)fminf(fmaxf(rintf(v1.z / scale), -127.f), 127.f);
        c.w = (char)fminf(fmaxf(rintf(v1.w / scale), -127.f), 127.f);
        orow[threadIdx.x + 256] = c;
    }
}

// ---------------- routing: order-exact positions, one wave per expert ----------------
__global__ __launch_bounds__(1024) void routing_kernel(
    const int* __restrict__ topki, const float* __restrict__ topkw,
    int* __restrict__ row_src, float* __restrict__ row_w, int* __restrict__ counts)
{
    int wv = threadIdx.x >> 6;   // expert id
    int lane = threadIdx.x & 63;
    int base = 0;
    for (int r0 = 0; r0 < T_TOK * TOPK; r0 += 64) {
        int r = r0 + lane;
        int e = topki[r];
        unsigned long long mask = __ballot(e == wv);
        int pre = __popcll(mask & ((1ULL << lane) - 1ULL));
        if (e == wv) {
            int pos = base + pre;
            if (pos < CAP) {
                row_src[wv * CAP + pos] = r >> 2;
                row_w[wv * CAP + pos] = topkw[r];
            }
        }
        base += __popcll(mask);
    }
    if (lane == 0) counts[wv] = (base < CAP) ? base : CAP;
}

// ---------------- GEMM1 (int8 x_q · gate_up) + swiglu, fused f32->i8 B-staging ----------------
__global__ __launch_bounds__(256) void gemm1_kernel(
    const char* __restrict__ xq, const float* __restrict__ xs,
    const int* __restrict__ row_src, const int* __restrict__ counts,
    const float* __restrict__ gup, const float* __restrict__ gus,
    const float* __restrict__ gub, const float* __restrict__ smo,
    float* __restrict__ act)
{
    int nt = blockIdx.x;   // 0..31 : 64 gate cols + matching 64 up cols
    int mt = blockIdx.y;   // 0..3
    int e  = blockIdx.z;
    int count = counts[e];
    int m0 = mt * BM;
    if (m0 >= count) return;

    __shared__ char sA[BM * BK];    // 8 KiB [row][k], 64B rows, chunk-swizzled
    __shared__ char sB[128 * BK];   // 8 KiB [n][k], chunk-swizzled

    int t = threadIdx.x;
    int lane = t & 63, w = t >> 6;
    int n16 = lane & 15, quad = lane >> 4;
    int swq = quad ^ ((n16 >> 1) & 3);     // swizzled 16B-chunk index for fragment reads

    // A staging via global_load_lds: LDS chunk c = op*256+t; row=c>>2, ks=c&3.
    // Source-side swizzle: fetch global chunk ks ^ ((row>>1)&3) so LDS[row][ks]
    // holds swizzled content matching the swq reader.
    const char* aSrc[2];
#pragma unroll
    for (int op = 0; op < 2; op++) {
        int c = op * 256 + t;
        int row = c >> 2, ks = c & 3;
        int ksg = ks ^ ((row >> 1) & 3);
        int gr = m0 + row;
        if (gr > count - 1) gr = count - 1;          // clamp: garbage rows' outputs discarded
        aSrc[op] = xq + (size_t)row_src[e * CAP + gr] * HID + ksg * 16;
    }

    // B staging (fused convert): thread t owns col bn = t>>1, k-half kb = (t&1)*32.
    int bn = t >> 1;
    int kb = (t & 1) * 32;
    int colg = nt * 64 + (bn & 63) + ((bn >= 64) ? INTER : 0);
    const float* bsrc = gup + (size_t)e * HID * (2 * INTER) + colg;
    int sn = (bn >> 1) & 3;
    char* wp0 = sB + bn * 64 + (((kb >> 4) + 0) ^ sn) * 16;
    char* wp1 = sB + bn * 64 + (((kb >> 4) + 1) ^ sn) * 16;

    iv4 acc[2][8];
#pragma unroll
    for (int i = 0; i < 2; i++)
#pragma unroll
        for (int j = 0; j < 8; j++) acc[i][j] = (iv4)0;

    for (int k0 = 0; k0 < HID; k0 += BK) {
        // issue B f32 loads (to regs) early
        float f[32];
#pragma unroll
        for (int i = 0; i < 32; i++)
            f[i] = bsrc[(size_t)(k0 + kb + i) * (2 * INTER)];
        __syncthreads();                    // previous iter's fragment reads done
        gl_lds16(aSrc[0] + k0, sA + w * 1024);
        gl_lds16(aSrc[1] + k0, sA + 4096 + w * 1024);
        int d[8];
#pragma unroll
        for (int j = 0; j < 8; j++)
            d[j] = pack4(f[4 * j], f[4 * j + 1], f[4 * j + 2], f[4 * j + 3]);
        *(int4*)wp0 = make_int4(d[0], d[1], d[2], d[3]);
        *(int4*)wp1 = make_int4(d[4], d[5], d[6], d[7]);
        __syncthreads();

        iv4 af[2], bf[8];
#pragma unroll
        for (int mf = 0; mf < 2; mf++)
            af[mf] = *(const iv4*)(sA + (w * 32 + mf * 16 + n16) * 64 + swq * 16);
#pragma unroll
        for (int nf = 0; nf < 8; nf++)
            bf[nf] = *(const iv4*)(sB + (nf * 16 + n16) * 64 + swq * 16);
#pragma unroll
        for (int mf = 0; mf < 2; mf++)
#pragma unroll
            for (int nf = 0; nf < 8; nf++)
                acc[mf][nf] = __builtin_amdgcn_mfma_i32_16x16x64_i8(af[mf], bf[nf], acc[mf][nf], 0, 0, 0);
    }

    // epilogue: exact-int dequant + swiglu + smooth
    const float* gsc = gus + (size_t)e * (2 * INTER);
    const float* gbi = gub + (size_t)e * (2 * INTER);
    const float* sms = smo + (size_t)e * INTER;
#pragma unroll
    for (int mf = 0; mf < 2; mf++) {
#pragma unroll
        for (int r = 0; r < 4; r++) {
            int gr = m0 + w * 32 + mf * 16 + quad * 4 + r;
            if (gr >= count) continue;
            float srow = xs[row_src[e * CAP + gr]];
            float* arow = act + (size_t)(e * CAP + gr) * INTER;
#pragma unroll
            for (int g = 0; g < 4; g++) {
                int col = nt * 64 + g * 16 + n16;
                float yg = (float)acc[mf][g][r]     * srow * gsc[col]         + gbi[col];
                float yu = (float)acc[mf][g + 4][r] * srow * gsc[INTER + col] + gbi[INTER + col];
                float gate = fminf(yg, GLIMIT);
                float up   = fminf(fmaxf(yu, -GLIMIT), GLIMIT);
                float sig  = 1.0f / (1.0f + expf(-GALPHA * gate));
                arow[col] = gate * sig * (up + 1.0f) * sms[col];
            }
        }
    }
}

// ---------------- per-row dynamic requant of act -> int8 ----------------
__global__ __launch_bounds__(256) void requant_kernel(
    const float* __restrict__ act, const int* __restrict__ counts,
    char* __restrict__ hq, float* __restrict__ hs)
{
    int b = blockIdx.x;           // e*CAP + c
    int e = b >> 9, c = b & (CAP - 1);
    if (c >= counts[e]) return;
    const float4* row = (const float4*)(act + (size_t)b * INTER);
    __shared__ float red[256];
    float4 v0 = row[threadIdx.x];
    float4 v1 = row[threadIdx.x + 256];
    float amax = fmaxf(fmaxf(fabsf(v0.x), fabsf(v0.y)), fmaxf(fabsf(v0.z), fabsf(v0.w)));
    amax = fmaxf(amax, fmaxf(fmaxf(fabsf(v1.x), fabsf(v1.y)), fmaxf(fabsf(v1.z), fabsf(v1.w))));
    red[threadIdx.x] = amax; __syncthreads();
    for (int s = 128; s > 0; s >>= 1) {
        if (threadIdx.x < s) red[threadIdx.x] = fmaxf(red[threadIdx.x], red[threadIdx.x + s]);
        __syncthreads();
    }
    float scale = fmaxf(red[0] / 127.0f, 1e-8f);
    if (threadIdx.x == 0) hs[b] = scale;
    char4* orow = (char4*)(hq + (size_t)b * INTER);
    {
        char4 cc;
        cc.x = (char)fminf(fmaxf(rintf(v0.x / scale), -127.f), 127.f);
        cc.y = (char)fminf(fmaxf(rintf(v0.y / scale), -127.f), 127.f);
        cc.z = (char)fminf(fmaxf(rintf(v0.z / scale), -127.f), 127.f);
        cc.w = (char)fminf(fmaxf(rintf(v0.w / scale), -127.f), 127.f);
        orow[threadIdx.x] = cc;
        cc.x = (char)fminf(fmaxf(rintf(v1.x / scale), -127.f), 127.f);
        cc.y = (char)fminf(fmaxf(rintf(v1.y / scale), -127.f), 127.f);
        cc.z = (char)fminf(fmaxf(rintf(v1.z / scale), -127.f), 127.f);
        cc.w = (char)fminf(fmaxf(rintf(v1.w / scale), -127.f), 127.f);
        orow[threadIdx.x + 256] = cc;
    }
}

// ---------------- GEMM2 (int8 h_q · down) + dequant + weighted combine ----------------
__global__ __launch_bounds__(256) void gemm2_kernel(
    const char* __restrict__ hq, const float* __restrict__ hs,
    const int* __restrict__ row_src, const float* __restrict__ row_w,
    const int* __restrict__ counts, const float* __restrict__ dwn,
    const float* __restrict__ dsc, const float* __restrict__ dbi,
    float* __restrict__ out)
{
    int nt = blockIdx.x;   // 0..15 : 128-wide H tile
    int mt = blockIdx.y;   // 0..3
    int e  = blockIdx.z;
    int count = counts[e];
    int m0 = mt * BM;
    if (m0 >= count) return;

    __shared__ char sA[BM * BK];
    __shared__ char sB[128 * BK];

    int t = threadIdx.x;
    int lane = t & 63, w = t >> 6;
    int n16 = lane & 15, quad = lane >> 4;
    int swq = quad ^ ((n16 >> 1) & 3);

    const char* aSrc[2];
#pragma unroll
    for (int op = 0; op < 2; op++) {
        int c = op * 256 + t;
        int row = c >> 2, ks = c & 3;
        int ksg = ks ^ ((row >> 1) & 3);
        int gr = m0 + row;
        if (gr > count - 1) gr = count - 1;
        aSrc[op] = hq + (size_t)(e * CAP + gr) * INTER + ksg * 16;
    }

    int bn = t >> 1;
    int kb = (t & 1) * 32;
    int colg = nt * 128 + bn;
    const float* bsrc = dwn + (size_t)e * INTER * HID + colg;
    int sn = (bn >> 1) & 3;
    char* wp0 = sB + bn * 64 + (((kb >> 4) + 0) ^ sn) * 16;
    char* wp1 = sB + bn * 64 + (((kb >> 4) + 1) ^ sn) * 16;

    iv4 acc[2][8];
#pragma unroll
    for (int i = 0; i < 2; i++)
#pragma unroll
        for (int j = 0; j < 8; j++) acc[i][j] = (iv4)0;

    for (int k0 = 0; k0 < INTER; k0 += BK) {
        float f[32];
#pragma unroll
        for (int i = 0; i < 32; i++)
            f[i] = bsrc[(size_t)(k0 + kb + i) * HID];
        __syncthreads();
        gl_lds16(aSrc[0] + k0, sA + w * 1024);
        gl_lds16(aSrc[1] + k0, sA + 4096 + w * 1024);
        int d[8];
#pragma unroll
        for (int j = 0; j < 8; j++)
            d[j] = pack4(f[4 * j], f[4 * j + 1], f[4 * j + 2], f[4 * j + 3]);
        *(int4*)wp0 = make_int4(d[0], d[1], d[2], d[3]);
        *(int4*)wp1 = make_int4(d[4], d[5], d[6], d[7]);
        __syncthreads();

        iv4 af[2], bf[8];
#pragma unroll
        for (int mf = 0; mf < 2; mf++)
            af[mf] = *(const iv4*)(sA + (w * 32 + mf * 16 + n16) * 64 + swq * 16);
#pragma unroll
        for (int nf = 0; nf < 8; nf++)
            bf[nf] = *(const iv4*)(sB + (nf * 16 + n16) * 64 + swq * 16);
#pragma unroll
        for (int mf = 0; mf < 2; mf++)
#pragma unroll
            for (int nf = 0; nf < 8; nf++)
                acc[mf][nf] = __builtin_amdgcn_mfma_i32_16x16x64_i8(af[mf], bf[nf], acc[mf][nf], 0, 0, 0);
    }

    const float* dscE = dsc + (size_t)e * HID;
    const float* dbiE = dbi + (size_t)e * HID;
#pragma unroll
    for (int mf = 0; mf < 2; mf++) {
#pragma unroll
        for (int r = 0; r < 4; r++) {
            int gr = m0 + w * 32 + mf * 16 + quad * 4 + r;
            if (gr >= count) continue;
            int ri = e * CAP + gr;
            float hsr = hs[ri];
            float wr  = row_w[ri];
            float* orow = out + (size_t)row_src[ri] * HID;
#pragma unroll
            for (int nf = 0; nf < 8; nf++) {
                int col = nt * 128 + nf * 16 + n16;
                float z = (float)acc[mf][nf][r] * hsr * dscE[col] + dbiE[col];
                atomicAdd(&orow[col], wr * z);
            }
        }
    }
}

// ---------------- launch ----------------
extern "C" void kernel_launch(void* const* d_in, const int* in_sizes, int n_in,
                              void* d_out, int out_size, void* d_ws, size_t ws_size,
                              hipStream_t stream)
{
    (void)in_sizes; (void)n_in; (void)out_size; (void)ws_size;
    const float* x   = (const float*)d_in[0];
    const float* rl  = (const float*)d_in[1];
    const float* gup = (const float*)d_in[2];
    const float* gus = (const float*)d_in[3];
    const float* gub = (const float*)d_in[4];
    const float* smo = (const float*)d_in[5];
    const float* dwn = (const float*)d_in[6];
    const float* dsc = (const float*)d_in[7];
    const float* dbi = (const float*)d_in[8];
    float* out = (float*)d_out;

    char* p = (char*)d_ws;
    auto carve = [&](size_t bytes) -> char* {
        char* r = p; p += (bytes + 255) & ~(size_t)255; return r;
    };
    char* xq       = carve((size_t)T_TOK * HID);
    float* xs      = (float*)carve((size_t)T_TOK * 4);
    int* topki     = (int*)carve((size_t)T_TOK * TOPK * 4);
    float* topkw   = (float*)carve((size_t)T_TOK * TOPK * 4);
    int* counts    = (int*)carve((size_t)NE * 4);
    int* rsrc      = (int*)carve((size_t)NE * CAP * 4);
    float* rw      = (float*)carve((size_t)NE * CAP * 4);
    float* actb    = (float*)carve((size_t)NE * CAP * INTER * 4);
    char* hq       = carve((size_t)NE * CAP * INTER);
    float* hsb     = (float*)carve((size_t)NE * CAP * 4);

    hipMemsetAsync(d_out, 0, (size_t)T_TOK * HID * 4, stream);
    gating_kernel<<<dim3((T_TOK + 255) / 256), 256, 0, stream>>>(rl, topki, topkw);
    quant_x_kernel<<<dim3(T_TOK), 256, 0, stream>>>(x, xq, xs);
    routing_kernel<<<dim3(1), 1024, 0, stream>>>(topki, topkw, rsrc, rw, counts);
    gemm1_kernel<<<dim3(INTER / 64, CAP / BM, NE), 256, 0, stream>>>(
        xq, xs, rsrc, counts, gup, gus, gub, smo, actb);
    requant_kernel<<<dim3(NE * CAP), 256, 0, stream>>>(actb, counts, hq, hsb);
    gemm2_kernel<<<dim3(HID / 128, CAP / BM, NE), 256, 0, stream>>>(
        hq, hsb, rsrc, rw, counts, dwn, dsc, dbi, out);
}

// Round 3
// 1065.910 us; speedup vs baseline: 1.1073x; 1.1073x over previous
//
#include <hip/hip_runtime.h>
#include <stdint.h>
#include <stddef.h>

#define T_TOK 1024
#define NE    16
#define TOPK  4
#define HID   2048
#define INTER 2048
#define CAP   512          // 2*T*K/E
#define GLIMIT 7.0f
#define GALPHA 1.702f

#define BM  128
#define BK  64             // i8 MFMA: K=64 per step

typedef __attribute__((ext_vector_type(4))) int   iv4;

// global_load_lds helper: 16B per lane, LDS dest = wave-uniform base + lane*16
typedef const __attribute__((address_space(1))) unsigned gl_u32;
typedef __attribute__((address_space(3))) unsigned lds_u32;
__device__ __forceinline__ void gl_lds16(const void* g, void* l) {
    __builtin_amdgcn_global_load_lds((gl_u32*)g, (lds_u32*)l, 16, 0, 0);
}

__device__ __forceinline__ int pack4(float a, float b, float c, float d) {
    int qa = (int)a, qb = (int)b, qc = (int)c, qd = (int)d;   // weights are integral f32
    return (qa & 255) | ((qb & 255) << 8) | ((qc & 255) << 16) | (qd << 24);
}

// ---------------- gating: softmax + top4 + renormalize ----------------
__global__ __launch_bounds__(256) void gating_kernel(
    const float* __restrict__ logits, int* __restrict__ topki, float* __restrict__ topkw)
{
    int t = blockIdx.x * 256 + threadIdx.x;
    if (t >= T_TOK) return;
    float l[NE];
#pragma unroll
    for (int e = 0; e < NE; e++) l[e] = logits[t * NE + e];
    unsigned used = 0;
    float val[TOPK]; int idx[TOPK];
#pragma unroll
    for (int k = 0; k < TOPK; k++) {
        float bv = -3.4e38f; int bi = 0;
#pragma unroll
        for (int e = 0; e < NE; e++) {
            bool ok = (((used >> e) & 1u) == 0u) && (l[e] > bv);
            bv = ok ? l[e] : bv;
            bi = ok ? e : bi;
        }
        used |= (1u << bi); idx[k] = bi; val[k] = bv;
    }
    float m = val[0];
    float s = 0.f, w[TOPK];
#pragma unroll
    for (int k = 0; k < TOPK; k++) { w[k] = expf(val[k] - m); s += w[k]; }
    float inv = 1.0f / s;
#pragma unroll
    for (int k = 0; k < TOPK; k++) { topki[t * TOPK + k] = idx[k]; topkw[t * TOPK + k] = w[k] * inv; }
}

// ---------------- per-token dynamic int8 quant ----------------
__global__ __launch_bounds__(256) void quant_x_kernel(
    const float* __restrict__ x, char* __restrict__ xq, float* __restrict__ xs)
{
    int t = blockIdx.x;
    const float4* row = (const float4*)(x + (size_t)t * HID);
    __shared__ float red[256];
    float4 v0 = row[threadIdx.x];
    float4 v1 = row[threadIdx.x + 256];
    float amax = fmaxf(fmaxf(fabsf(v0.x), fabsf(v0.y)), fmaxf(fabsf(v0.z), fabsf(v0.w)));
    amax = fmaxf(amax, fmaxf(fmaxf(fabsf(v1.x), fabsf(v1.y)), fmaxf(fabsf(v1.z), fabsf(v1.w))));
    red[threadIdx.x] = amax; __syncthreads();
    for (int s = 128; s > 0; s >>= 1) {
        if (threadIdx.x < s) red[threadIdx.x] = fmaxf(red[threadIdx.x], red[threadIdx.x + s]);
        __syncthreads();
    }
    float scale = fmaxf(red[0] / 127.0f, 1e-8f);
    if (threadIdx.x == 0) xs[t] = scale;
    char4* orow = (char4*)(xq + (size_t)t * HID);
    {
        char4 c;
        c.x = (char)fminf(fmaxf(rintf(v0.x / scale), -127.f), 127.f);
        c.y = (char)fminf(fmaxf(rintf(v0.y / scale), -127.f), 127.f);
        c.z = (char)fminf(fmaxf(rintf(v0.z / scale), -127.f), 127.f);
        c.w = (char)fminf(fmaxf(rintf(v0.w / scale), -127.f), 127.f);
        orow[threadIdx.x] = c;
        c.x = (char)fminf(fmaxf(rintf(v1.x / scale), -127.f), 127.f);
        c.y = (char)fminf(fmaxf(rintf(v1.y / scale), -127.f), 127.f);
        c.z = (char)fminf(fmaxf(rintf(v1.z / scale), -127.f), 127.f);
        c.w = (char)fminf(fmaxf(rintf(v1.w / scale), -127.f), 127.f);
        orow[threadIdx.x + 256] = c;
    }
}

// ---------------- routing: order-exact positions, one wave per expert ----------------
__global__ __launch_bounds__(1024) void routing_kernel(
    const int* __restrict__ topki, const float* __restrict__ topkw,
    int* __restrict__ row_src, float* __restrict__ row_w, int* __restrict__ counts)
{
    int wv = threadIdx.x >> 6;   // expert id
    int lane = threadIdx.x & 63;
    int base = 0;
    for (int r0 = 0; r0 < T_TOK * TOPK; r0 += 64) {
        int r = r0 + lane;
        int e = topki[r];
        unsigned long long mask = __ballot(e == wv);
        int pre = __popcll(mask & ((1ULL << lane) - 1ULL));
        if (e == wv) {
            int pos = base + pre;
            if (pos < CAP) {
                row_src[wv * CAP + pos] = r >> 2;
                row_w[wv * CAP + pos] = topkw[r];
            }
        }
        base += __popcll(mask);
    }
    if (lane == 0) counts[wv] = (base < CAP) ? base : CAP;
}

// ---------------- GEMM1 (int8 x_q · gate_up) + swiglu, fused pipelined B-staging ----------------
__global__ __launch_bounds__(256) void gemm1_kernel(
    const char* __restrict__ xq, const float* __restrict__ xs,
    const int* __restrict__ row_src, const int* __restrict__ counts,
    const float* __restrict__ gup, const float* __restrict__ gus,
    const float* __restrict__ gub, const float* __restrict__ smo,
    float* __restrict__ act)
{
    int nt = blockIdx.x;   // 0..31 : 64 gate cols + matching 64 up cols
    int mt = blockIdx.y;   // 0..3
    int e  = blockIdx.z;
    int count = counts[e];
    int m0 = mt * BM;
    if (m0 >= count) return;

    __shared__ char sA[BM * BK];    // 8 KiB [row][k], 64B rows, chunk-swizzled
    __shared__ char sB[128 * BK];   // 8 KiB [n][k], chunk-swizzled

    int t = threadIdx.x;
    int lane = t & 63, w = t >> 6;
    int n16 = lane & 15, quad = lane >> 4;
    int swq = quad ^ ((n16 >> 1) & 3);     // swizzled 16B-chunk index for fragment reads

    // A staging via global_load_lds: LDS chunk c = op*256+t; row=c>>2, ks=c&3.
    // Source-side swizzle: global chunk ks ^ ((row>>1)&3) lands at LDS[row][ks].
    const char* aSrc[2];
#pragma unroll
    for (int op = 0; op < 2; op++) {
        int c = op * 256 + t;
        int row = c >> 2, ks = c & 3;
        int ksg = ks ^ ((row >> 1) & 3);
        int gr = m0 + row;
        if (gr > count - 1) gr = count - 1;          // clamp: garbage rows' outputs discarded
        aSrc[op] = xq + (size_t)row_src[e * CAP + gr] * HID + ksg * 16;
    }

    // B staging (fused f32->i8): thread owns col bc for gate and up, k-chunk w.
    // Per load instruction the wave reads 64 consecutive cols = one 256B segment.
    int bc = t & 63;
    const float* bgate = gup + (size_t)e * HID * (2 * INTER) + nt * 64 + bc;
    const float* bup   = bgate + INTER;
    int sn = (bc >> 1) & 3;
    char* wpg = sB + bc * 64        + (w ^ sn) * 16;   // gate row bc, phys chunk w^s
    char* wpu = sB + (64 + bc) * 64 + (w ^ sn) * 16;   // up   row 64+bc

    iv4 acc[2][8];
#pragma unroll
    for (int i = 0; i < 2; i++)
#pragma unroll
        for (int j = 0; j < 8; j++) acc[i][j] = (iv4)0;

    float f[32];
    // prologue: load B(0)
#pragma unroll
    for (int i = 0; i < 16; i++) {
        f[i]      = bgate[(size_t)(w * 16 + i) * (2 * INTER)];
        f[16 + i] = bup  [(size_t)(w * 16 + i) * (2 * INTER)];
    }

    for (int kt = 0; kt < HID / BK; kt++) {
        __syncthreads();                    // previous iter's fragment reads done
        gl_lds16(aSrc[0] + kt * BK, sA + w * 1024);
        gl_lds16(aSrc[1] + kt * BK, sA + 4096 + w * 1024);
        {
            int d0[4], d1[4];
#pragma unroll
            for (int j = 0; j < 4; j++) {
                d0[j] = pack4(f[4 * j],      f[4 * j + 1],      f[4 * j + 2],      f[4 * j + 3]);
                d1[j] = pack4(f[16 + 4 * j], f[16 + 4 * j + 1], f[16 + 4 * j + 2], f[16 + 4 * j + 3]);
            }
            *(int4*)wpg = make_int4(d0[0], d0[1], d0[2], d0[3]);
            *(int4*)wpu = make_int4(d1[0], d1[1], d1[2], d1[3]);
        }
        __syncthreads();                    // drains gl_lds + ds_writes

        // fragment reads first (critical path to MFMA) ...
        iv4 af[2], bf[8];
#pragma unroll
        for (int mf = 0; mf < 2; mf++)
            af[mf] = *(const iv4*)(sA + (w * 32 + mf * 16 + n16) * 64 + swq * 16);
#pragma unroll
        for (int nf = 0; nf < 8; nf++)
            bf[nf] = *(const iv4*)(sB + (nf * 16 + n16) * 64 + swq * 16);

        // ... then issue next-step B loads: latency hides under the MFMAs below
        int kn = (kt + 1 < HID / BK) ? (kt + 1) : kt;
        size_t krow = (size_t)(kn * BK) * (2 * INTER);
#pragma unroll
        for (int i = 0; i < 16; i++) {
            f[i]      = bgate[krow + (size_t)(w * 16 + i) * (2 * INTER)];
            f[16 + i] = bup  [krow + (size_t)(w * 16 + i) * (2 * INTER)];
        }

#pragma unroll
        for (int mf = 0; mf < 2; mf++)
#pragma unroll
            for (int nf = 0; nf < 8; nf++)
                acc[mf][nf] = __builtin_amdgcn_mfma_i32_16x16x64_i8(af[mf], bf[nf], acc[mf][nf], 0, 0, 0);
    }

    // epilogue: exact-int dequant + swiglu + smooth
    const float* gsc = gus + (size_t)e * (2 * INTER);
    const float* gbi = gub + (size_t)e * (2 * INTER);
    const float* sms = smo + (size_t)e * INTER;
#pragma unroll
    for (int mf = 0; mf < 2; mf++) {
#pragma unroll
        for (int r = 0; r < 4; r++) {
            int gr = m0 + w * 32 + mf * 16 + quad * 4 + r;
            if (gr >= count) continue;
            float srow = xs[row_src[e * CAP + gr]];
            float* arow = act + (size_t)(e * CAP + gr) * INTER;
#pragma unroll
            for (int g = 0; g < 4; g++) {
                int col = nt * 64 + g * 16 + n16;
                float yg = (float)acc[mf][g][r]     * srow * gsc[col]         + gbi[col];
                float yu = (float)acc[mf][g + 4][r] * srow * gsc[INTER + col] + gbi[INTER + col];
                float gate = fminf(yg, GLIMIT);
                float up   = fminf(fmaxf(yu, -GLIMIT), GLIMIT);
                float sig  = 1.0f / (1.0f + expf(-GALPHA * gate));
                arow[col] = gate * sig * (up + 1.0f) * sms[col];
            }
        }
    }
}

// ---------------- per-row dynamic requant of act -> int8 ----------------
__global__ __launch_bounds__(256) void requant_kernel(
    const float* __restrict__ act, const int* __restrict__ counts,
    char* __restrict__ hq, float* __restrict__ hs)
{
    int b = blockIdx.x;           // e*CAP + c
    int e = b >> 9, c = b & (CAP - 1);
    if (c >= counts[e]) return;
    const float4* row = (const float4*)(act + (size_t)b * INTER);
    __shared__ float red[256];
    float4 v0 = row[threadIdx.x];
    float4 v1 = row[threadIdx.x + 256];
    float amax = fmaxf(fmaxf(fabsf(v0.x), fabsf(v0.y)), fmaxf(fabsf(v0.z), fabsf(v0.w)));
    amax = fmaxf(amax, fmaxf(fmaxf(fabsf(v1.x), fabsf(v1.y)), fmaxf(fabsf(v1.z), fabsf(v1.w))));
    red[threadIdx.x] = amax; __syncthreads();
    for (int s = 128; s > 0; s >>= 1) {
        if (threadIdx.x < s) red[threadIdx.x] = fmaxf(red[threadIdx.x], red[threadIdx.x + s]);
        __syncthreads();
    }
    float scale = fmaxf(red[0] / 127.0f, 1e-8f);
    if (threadIdx.x == 0) hs[b] = scale;
    char4* orow = (char4*)(hq + (size_t)b * INTER);
    {
        char4 cc;
        cc.x = (char)fminf(fmaxf(rintf(v0.x / scale), -127.f), 127.f);
        cc.y = (char)fminf(fmaxf(rintf(v0.y / scale), -127.f), 127.f);
        cc.z = (char)fminf(fmaxf(rintf(v0.z / scale), -127.f), 127.f);
        cc.w = (char)fminf(fmaxf(rintf(v0.w / scale), -127.f), 127.f);
        orow[threadIdx.x] = cc;
        cc.x = (char)fminf(fmaxf(rintf(v1.x / scale), -127.f), 127.f);
        cc.y = (char)fminf(fmaxf(rintf(v1.y / scale), -127.f), 127.f);
        cc.z = (char)fminf(fmaxf(rintf(v1.z / scale), -127.f), 127.f);
        cc.w = (char)fminf(fmaxf(rintf(v1.w / scale), -127.f), 127.f);
        orow[threadIdx.x + 256] = cc;
    }
}

// ---------------- GEMM2 (int8 h_q · down) + dequant + weighted combine ----------------
__global__ __launch_bounds__(256) void gemm2_kernel(
    const char* __restrict__ hq, const float* __restrict__ hs,
    const int* __restrict__ row_src, const float* __restrict__ row_w,
    const int* __restrict__ counts, const float* __restrict__ dwn,
    const float* __restrict__ dsc, const float* __restrict__ dbi,
    float* __restrict__ out)
{
    int nt = blockIdx.x;   // 0..15 : 128-wide H tile
    int mt = blockIdx.y;   // 0..3
    int e  = blockIdx.z;
    int count = counts[e];
    int m0 = mt * BM;
    if (m0 >= count) return;

    __shared__ char sA[BM * BK];
    __shared__ char sB[128 * BK];

    int t = threadIdx.x;
    int lane = t & 63, w = t >> 6;
    int n16 = lane & 15, quad = lane >> 4;
    int swq = quad ^ ((n16 >> 1) & 3);

    const char* aSrc[2];
#pragma unroll
    for (int op = 0; op < 2; op++) {
        int c = op * 256 + t;
        int row = c >> 2, ks = c & 3;
        int ksg = ks ^ ((row >> 1) & 3);
        int gr = m0 + row;
        if (gr > count - 1) gr = count - 1;
        aSrc[op] = hq + (size_t)(e * CAP + gr) * INTER + ksg * 16;
    }

    // B staging: thread owns col bc = t&127, k-half = t>>7 (rows half*32..+31).
    int bc = t & 127;
    int half = t >> 7;
    const float* bsrc = dwn + (size_t)e * INTER * HID + nt * 128 + bc;
    int sn = (bc >> 1) & 3;
    char* wp0 = sB + bc * 64 + ((half * 2 + 0) ^ sn) * 16;
    char* wp1 = sB + bc * 64 + ((half * 2 + 1) ^ sn) * 16;

    iv4 acc[2][8];
#pragma unroll
    for (int i = 0; i < 2; i++)
#pragma unroll
        for (int j = 0; j < 8; j++) acc[i][j] = (iv4)0;

    float f[32];
#pragma unroll
    for (int i = 0; i < 32; i++)
        f[i] = bsrc[(size_t)(half * 32 + i) * HID];

    for (int kt = 0; kt < INTER / BK; kt++) {
        __syncthreads();
        gl_lds16(aSrc[0] + kt * BK, sA + w * 1024);
        gl_lds16(aSrc[1] + kt * BK, sA + 4096 + w * 1024);
        {
            int d[8];
#pragma unroll
            for (int j = 0; j < 8; j++)
                d[j] = pack4(f[4 * j], f[4 * j + 1], f[4 * j + 2], f[4 * j + 3]);
            *(int4*)wp0 = make_int4(d[0], d[1], d[2], d[3]);
            *(int4*)wp1 = make_int4(d[4], d[5], d[6], d[7]);
        }
        __syncthreads();

        iv4 af[2], bf[8];
#pragma unroll
        for (int mf = 0; mf < 2; mf++)
            af[mf] = *(const iv4*)(sA + (w * 32 + mf * 16 + n16) * 64 + swq * 16);
#pragma unroll
        for (int nf = 0; nf < 8; nf++)
            bf[nf] = *(const iv4*)(sB + (nf * 16 + n16) * 64 + swq * 16);

        int kn = (kt + 1 < INTER / BK) ? (kt + 1) : kt;
        size_t krow = (size_t)(kn * BK) * HID;
#pragma unroll
        for (int i = 0; i < 32; i++)
            f[i] = bsrc[krow + (size_t)(half * 32 + i) * HID];

#pragma unroll
        for (int mf = 0; mf < 2; mf++)
#pragma unroll
            for (int nf = 0; nf < 8; nf++)
                acc[mf][nf] = __builtin_amdgcn_mfma_i32_16x16x64_i8(af[mf], bf[nf], acc[mf][nf], 0, 0, 0);
    }

    const float* dscE = dsc + (size_t)e * HID;
    const float* dbiE = dbi + (size_t)e * HID;
#pragma unroll
    for (int mf = 0; mf < 2; mf++) {
#pragma unroll
        for (int r = 0; r < 4; r++) {
            int gr = m0 + w * 32 + mf * 16 + quad * 4 + r;
            if (gr >= count) continue;
            int ri = e * CAP + gr;
            float hsr = hs[ri];
            float wr  = row_w[ri];
            float* orow = out + (size_t)row_src[ri] * HID;
#pragma unroll
            for (int nf = 0; nf < 8; nf++) {
                int col = nt * 128 + nf * 16 + n16;
                float z = (float)acc[mf][nf][r] * hsr * dscE[col] + dbiE[col];
                atomicAdd(&orow[col], wr * z);
            }
        }
    }
}

// ---------------- launch ----------------
extern "C" void kernel_launch(void* const* d_in, const int* in_sizes, int n_in,
                              void* d_out, int out_size, void* d_ws, size_t ws_size,
                              hipStream_t stream)
{
    (void)in_sizes; (void)n_in; (void)out_size; (void)ws_size;
    const float* x   = (const float*)d_in[0];
    const float* rl  = (const float*)d_in[1];
    const float* gup = (const float*)d_in[2];
    const float* gus = (const float*)d_in[3];
    const float* gub = (const float*)d_in[4];
    const float* smo = (const float*)d_in[5];
    const float* dwn = (const float*)d_in[6];
    const float* dsc = (const float*)d_in[7];
    const float* dbi = (const float*)d_in[8];
    float* out = (float*)d_out;

    char* p = (char*)d_ws;
    auto carve = [&](size_t bytes) -> char* {
        char* r = p; p += (bytes + 255) & ~(size_t)255; return r;
    };
    char* xq       = carve((size_t)T_TOK * HID);
    float* xs      = (float*)carve((size_t)T_TOK * 4);
    int* topki     = (int*)carve((size_t)T_TOK * TOPK * 4);
    float* topkw   = (float*)carve((size_t)T_TOK * TOPK * 4);
    int* counts    = (int*)carve((size_t)NE * 4);
    int* rsrc      = (int*)carve((size_t)NE * CAP * 4);
    float* rw      = (float*)carve((size_t)NE * CAP * 4);
    float* actb    = (float*)carve((size_t)NE * CAP * INTER * 4);
    char* hq       = carve((size_t)NE * CAP * INTER);
    float* hsb     = (float*)carve((size_t)NE * CAP * 4);

    hipMemsetAsync(d_out, 0, (size_t)T_TOK * HID * 4, stream);
    gating_kernel<<<dim3((T_TOK + 255) / 256), 256, 0, stream>>>(rl, topki, topkw);
    quant_x_kernel<<<dim3(T_TOK), 256, 0, stream>>>(x, xq, xs);
    routing_kernel<<<dim3(1), 1024, 0, stream>>>(topki, topkw, rsrc, rw, counts);
    gemm1_kernel<<<dim3(INTER / 64, CAP / BM, NE), 256, 0, stream>>>(
        xq, xs, rsrc, counts, gup, gus, gub, smo, actb);
    requant_kernel<<<dim3(NE * CAP), 256, 0, stream>>>(actb, counts, hq, hsb);
    gemm2_kernel<<<dim3(HID / 128, CAP / BM, NE), 256, 0, stream>>>(
        hq, hsb, rsrc, rw, counts, dwn, dsc, dbi, out);
}